// Round 10
// baseline (746.992 us; speedup 1.0000x reference)
//
#include <hip/hip_runtime.h>
#include <math.h>

// SLIC superpixel segmentation — bit-faithful f32 reimplementation of the JAX ref
// (XLA CPU semantics). Numerics decisions, all aimed at exact label match:
//  - dot(feats, centers) replicates Eigen sgemm: sequential k=0..4 FMA chain.
//  - f_sq / c_sq: rounded squares, sequential adds, NO fma (fp contract off).
//  - d = (f_sq + c_sq) - 2*dot, three separately-rounded ops.
//  - strict-< argmin (first occurrence, == jnp.argmin).
//  - segment_sum: EXACT ascending-pixel-index sequential adds per cluster.
// R10: the global counting sort (hist + offsets + scatter kernel + sortedF
// round-trip, ~23us x20 dispatches in R9) is replaced by a TILE-LOCAL sort
// fused into assign: each 1024-px tile compacts its pixels into per-label
// segments (tileBuf) + (cnt,start) descriptors. Update concatenates the 49
// tile segments in ascending tile order == ascending global pixel order ->
// add order bit-identical. No labels/hist/offsets buffers; 22 dispatches.

#pragma clang fp contract(off)

#define BATCH 8
#define HH 224
#define WW 224
#define HWPIX (HH * WW)        // 50176
#define KSEG 100
#define NTILE 49               // 1024-px tiles per batch
#define NITER 10
#define UCH 2048               // update chunk (>= max per-tile cnt 1024)

__device__ __forceinline__ float get_ratio() {
    double S = sqrt((double)(HH * WW) / (double)KSEG);
    return (float)(10.0 / S);
}

__global__ void k_init(const float* __restrict__ img, float* __restrict__ centers) {
#pragma clang fp contract(off)
    int b = blockIdx.x;
    int k = threadIdx.x;
    if (k >= KSEG) return;
    int i = k / 10, j = k % 10;
    int y = (int)floor(((i + 0.5) * (double)HH) / 10.0);
    int x = (int)floor(((j + 0.5) * (double)WW) / 10.0);
    float ratio = get_ratio();
    int n = y * WW + x;
    const float* p = img + ((size_t)b * HWPIX + n) * 3;
    float* c = centers + (b * KSEG + k) * 5;
    c[0] = (float)y * ratio;
    c[1] = (float)x * ratio;
    c[2] = p[0];
    c[3] = p[1];
    c[4] = p[2];
}

// 4 pixels/thread: n = tile*1024 + p*256 + tid. Ascending n == lex (p, w, lane).
// mode 0: argmin + tile-local counting sort -> tileBuf segments + cnt/start.
// mode 1: final outputs only.
__global__ void k_assign(const float* __restrict__ img, const float* __restrict__ centers,
                         float* __restrict__ tileBuf, int* __restrict__ cntT,
                         int* __restrict__ startT, float* __restrict__ outLab,
                         float* __restrict__ outMean, int mode) {
#pragma clang fp contract(off)
    __shared__ float c8[KSEG * 8];   // [c0..c4, csq, pad, pad]
    __shared__ int whist[16 * KSEG]; // group g = p*4 + w, lex order == pixel order
    __shared__ int tilecnt[KSEG];
    __shared__ int loffs[KSEG];
    int b = blockIdx.y, tile = blockIdx.x, tid = threadIdx.x;
    int lane = tid & 63, w = tid >> 6;

    for (int i = tid; i < KSEG * 5; i += 256) {
        int k = i / 5, f = i - 5 * k;
        c8[k * 8 + f] = centers[(size_t)b * KSEG * 5 + i];
    }
    if (mode == 0)
        for (int i = tid; i < 16 * KSEG; i += 256) whist[i] = 0;
    __syncthreads();
    if (tid < KSEG) {
        const float* ck = c8 + tid * 8;
        float s = ck[0] * ck[0];             // XLA fused mul+reduce: no fma, seq adds
        s = s + ck[1] * ck[1];
        s = s + ck[2] * ck[2];
        s = s + ck[3] * ck[3];
        s = s + ck[4] * ck[4];
        c8[tid * 8 + 5] = s;
    }
    __syncthreads();

    float ratio = get_ratio();
    int n0 = tile * 1024 + tid;
    float yf[4], xf[4], rr[4], gg[4], bb[4], fsq[4], dmin[4];
    int kb[4];
#pragma unroll
    for (int p = 0; p < 4; ++p) {
        int n = n0 + p * 256;
        int y = n / WW, x = n - y * WW;
        yf[p] = (float)y * ratio;
        xf[p] = (float)x * ratio;
        const float* pp = img + ((size_t)b * HWPIX + n) * 3;
        rr[p] = pp[0]; gg[p] = pp[1]; bb[p] = pp[2];
        float s = yf[p] * yf[p];             // no fma, seq adds (XLA reduce)
        s = s + xf[p] * xf[p];
        s = s + rr[p] * rr[p];
        s = s + gg[p] * gg[p];
        s = s + bb[p] * bb[p];
        fsq[p] = s;
        dmin[p] = INFINITY;
        kb[p] = 0;
    }

    for (int k = 0; k < KSEG; ++k) {
        float4 v0 = *reinterpret_cast<const float4*>(&c8[k * 8]);  // ds_read_b128
        float c4v = c8[k * 8 + 4];
        float csqv = c8[k * 8 + 5];
#pragma unroll
        for (int p = 0; p < 4; ++p) {
            // Eigen sgemm micro-kernel: sequential FMA chain over contracted dim
            float dot = yf[p] * v0.x;        // == fma(yf, c0, 0)
            dot = __fmaf_rn(xf[p], v0.y, dot);
            dot = __fmaf_rn(rr[p], v0.z, dot);
            dot = __fmaf_rn(gg[p], v0.w, dot);
            dot = __fmaf_rn(bb[p], c4v, dot);
            float d = (fsq[p] + csqv) - 2.0f * dot;   // three separately-rounded ops
            if (d < dmin[p]) { dmin[p] = d; kb[p] = k; }  // strict < == jnp.argmin
        }
    }

    if (mode == 1) {
#pragma unroll
        for (int p = 0; p < 4; ++p) {
            int n = n0 + p * 256;
            outLab[(size_t)b * HWPIX + n] = (float)kb[p];
            float* om = outMean + ((size_t)b * HWPIX + n) * 3;
            om[0] = c8[kb[p] * 8 + 2];
            om[1] = c8[kb[p] * 8 + 3];
            om[2] = c8[kb[p] * 8 + 4];
        }
        return;
    }

    // ---- tile-local stable counting sort (order: p, wave, lane == ascending n)
    int rank_w[4], cnt_w[4];
#pragma unroll
    for (int p = 0; p < 4; ++p) { rank_w[p] = 0; cnt_w[p] = 0; }
    for (int l = 0; l < 64; ++l) {
#pragma unroll
        for (int p = 0; p < 4; ++p) {
            int ll = __shfl(kb[p], l);
            if (ll == kb[p]) { cnt_w[p]++; if (l < lane) rank_w[p]++; }
        }
    }
#pragma unroll
    for (int p = 0; p < 4; ++p)
        if (rank_w[p] == 0) whist[(p * 4 + w) * KSEG + kb[p]] = cnt_w[p];
    __syncthreads();
    if (tid < KSEG) {
        int s = 0;
        for (int g = 0; g < 16; ++g) s += whist[g * KSEG + tid];
        tilecnt[tid] = s;
    }
    __syncthreads();
    if (tid < KSEG) {
        int bsum = 0;
        for (int j = 0; j < tid; ++j) bsum += tilecnt[j];
        loffs[tid] = bsum;
        cntT[((size_t)b * KSEG + tid) * NTILE + tile] = tilecnt[tid];
        startT[((size_t)b * KSEG + tid) * NTILE + tile] = bsum;
    }
    __syncthreads();

    float* tb = tileBuf + (size_t)(b * NTILE + tile) * 5 * 1024;
#pragma unroll
    for (int p = 0; p < 4; ++p) {
        int g = p * 4 + w;
        int r = rank_w[p];
        for (int g2 = 0; g2 < g; ++g2) r += whist[g2 * KSEG + kb[p]];
        int pos = loffs[kb[p]] + r;
        tb[0 * 1024 + pos] = yf[p];
        tb[1 * 1024 + pos] = xf[p];
        tb[2 * 1024 + pos] = rr[p];
        tb[3 * 1024 + pos] = gg[p];
        tb[4 * 1024 + pos] = bb[p];
    }
}

// One block per (batch,cluster): concatenate the 49 tile segments (ascending
// tile order == ascending pixel order) into LDS, 5-lane exact serial chains.
__global__ void k_update(const float* __restrict__ tileBuf, const int* __restrict__ cntT,
                         const int* __restrict__ startT, float* __restrict__ centers) {
#pragma clang fp contract(off)
    __shared__ int cntL[NTILE], srcL[NTILE], dstL[NTILE];
    __shared__ float ubuf[5][UCH + 1];
    __shared__ int totalS;
    int k = blockIdx.x, b = blockIdx.y, tid = threadIdx.x;
    int lane = tid & 63;

    if (tid < 64) {
        int c = (lane < NTILE) ? cntT[((size_t)b * KSEG + k) * NTILE + lane] : 0;
        int s = (lane < NTILE) ? startT[((size_t)b * KSEG + k) * NTILE + lane] : 0;
        int incl = c;
        for (int d = 1; d < 64; d <<= 1) {   // Hillis-Steele inclusive scan
            int t = __shfl_up(incl, d);
            if (lane >= d) incl += t;
        }
        if (lane < NTILE) { cntL[lane] = c; srcL[lane] = s; dstL[lane] = incl - c; }
        if (lane == 63) totalS = incl;
    }
    __syncthreads();
    int total = totalS;

    float acc = 0.f;
    int tc = 0;
    while (tc < NTILE) {
        int te = tc, sum = 0;
        while (te < NTILE && sum + cntL[te] <= UCH) { sum += cntL[te]; te++; }
        int chunkbase = dstL[tc];
        int ntasks = (te - tc) * 5;
        for (int task = tid; task < ntasks; task += 256) {
            int q = task / 5;
            int tt = tc + q, ch = task - 5 * q;
            const float* src = tileBuf + ((size_t)(b * NTILE + tt) * 5 + ch) * 1024 + srcL[tt];
            int c = cntL[tt], doff = dstL[tt] - chunkbase;
            for (int i = 0; i < c; ++i) ubuf[ch][doff + i] = src[i];
        }
        __syncthreads();
        if (tid < 5) {
            float a = acc;
            const float* bp = ubuf[tid];
            for (int i = 0; i < sum; ++i) a = a + bp[i];  // exact ascending chain
            acc = a;
        }
        __syncthreads();
        tc = te;
    }
    if (tid < 5 && total > 0) {              // where(counts>0, sums/counts, old)
        centers[(b * KSEG + k) * 5 + tid] = acc / (float)total;
    }
}

extern "C" void kernel_launch(void* const* d_in, const int* in_sizes, int n_in,
                              void* d_out, int out_size, void* d_ws, size_t ws_size,
                              hipStream_t stream) {
    const float* img = (const float*)d_in[0];
    float* outLab = (float*)d_out;                         // [8,224,224] labels as f32
    float* outMean = outLab + (size_t)BATCH * HWPIX;       // [8,224,224,3]

    char* ws = (char*)d_ws;
    float* centers = (float*)ws;  ws += (size_t)BATCH * KSEG * 5 * sizeof(float);
    float* tileBuf = (float*)ws;  ws += (size_t)BATCH * NTILE * 5 * 1024 * sizeof(float);
    int* cntT      = (int*)ws;    ws += (size_t)BATCH * KSEG * NTILE * sizeof(int);
    int* startT    = (int*)ws;    ws += (size_t)BATCH * KSEG * NTILE * sizeof(int);

    k_init<<<dim3(BATCH), 128, 0, stream>>>(img, centers);
    for (int it = 0; it < NITER; ++it) {
        k_assign<<<dim3(NTILE, BATCH), 256, 0, stream>>>(img, centers, tileBuf, cntT,
                                                         startT, outLab, outMean, 0);
        k_update<<<dim3(KSEG, BATCH), 256, 0, stream>>>(tileBuf, cntT, startT, centers);
    }
    k_assign<<<dim3(NTILE, BATCH), 256, 0, stream>>>(img, centers, tileBuf, cntT,
                                                     startT, outLab, outMean, 1);
}

// Round 11
// 515.176 us; speedup vs baseline: 1.4500x; 1.4500x over previous
//
#include <hip/hip_runtime.h>
#include <math.h>

// SLIC superpixel segmentation — bit-faithful f32 reimplementation of the JAX ref
// (XLA CPU semantics). Numerics decisions, all aimed at exact label match:
//  - dot(feats, centers) replicates Eigen sgemm: sequential k=0..4 FMA chain.
//  - f_sq / c_sq: rounded squares, sequential adds, NO fma (fp contract off).
//  - d = (f_sq + c_sq) - 2*dot, three separately-rounded ops.
//  - strict-< argmin (first occurrence, == jnp.argmin).
//  - segment_sum: EXACT ascending-pixel-index sequential adds per cluster.
// Structure: assign fuses a tile-local counting sort (1024-px tiles -> per-label
// segments in tileBuf + cnt/start descriptors); update concatenates the 49 tile
// segments in ascending tile order == ascending pixel order (bit-identical).
// R11: fix R10's update gather (per-thread serial segment copies, uncoalesced,
// ~50us + 68k LDS conflicts) with an OUTPUT-INDEXED copy: thread j binary-
// searches dstL (6 LDS steps) -> coalesced tileBuf loads, conflict-free ubuf
// writes. Values and add order unchanged.

#pragma clang fp contract(off)

#define BATCH 8
#define HH 224
#define WW 224
#define HWPIX (HH * WW)        // 50176
#define KSEG 100
#define NTILE 49               // 1024-px tiles per batch
#define NITER 10
#define UCH 1024               // update output chunk; LDS 5*(1024+1)*4B = 20.5KB

__device__ __forceinline__ float get_ratio() {
    double S = sqrt((double)(HH * WW) / (double)KSEG);
    return (float)(10.0 / S);
}

__global__ void k_init(const float* __restrict__ img, float* __restrict__ centers) {
#pragma clang fp contract(off)
    int b = blockIdx.x;
    int k = threadIdx.x;
    if (k >= KSEG) return;
    int i = k / 10, j = k % 10;
    int y = (int)floor(((i + 0.5) * (double)HH) / 10.0);
    int x = (int)floor(((j + 0.5) * (double)WW) / 10.0);
    float ratio = get_ratio();
    int n = y * WW + x;
    const float* p = img + ((size_t)b * HWPIX + n) * 3;
    float* c = centers + (b * KSEG + k) * 5;
    c[0] = (float)y * ratio;
    c[1] = (float)x * ratio;
    c[2] = p[0];
    c[3] = p[1];
    c[4] = p[2];
}

// 4 pixels/thread: n = tile*1024 + p*256 + tid. Ascending n == lex (p, w, lane).
// mode 0: argmin + tile-local counting sort -> tileBuf segments + cnt/start.
// mode 1: final outputs only.
__global__ void k_assign(const float* __restrict__ img, const float* __restrict__ centers,
                         float* __restrict__ tileBuf, int* __restrict__ cntT,
                         int* __restrict__ startT, float* __restrict__ outLab,
                         float* __restrict__ outMean, int mode) {
#pragma clang fp contract(off)
    __shared__ float c8[KSEG * 8];   // [c0..c4, csq, pad, pad]
    __shared__ int whist[16 * KSEG]; // group g = p*4 + w, lex order == pixel order
    __shared__ int tilecnt[KSEG];
    __shared__ int loffs[KSEG];
    int b = blockIdx.y, tile = blockIdx.x, tid = threadIdx.x;
    int lane = tid & 63, w = tid >> 6;

    for (int i = tid; i < KSEG * 5; i += 256) {
        int k = i / 5, f = i - 5 * k;
        c8[k * 8 + f] = centers[(size_t)b * KSEG * 5 + i];
    }
    if (mode == 0)
        for (int i = tid; i < 16 * KSEG; i += 256) whist[i] = 0;
    __syncthreads();
    if (tid < KSEG) {
        const float* ck = c8 + tid * 8;
        float s = ck[0] * ck[0];             // XLA fused mul+reduce: no fma, seq adds
        s = s + ck[1] * ck[1];
        s = s + ck[2] * ck[2];
        s = s + ck[3] * ck[3];
        s = s + ck[4] * ck[4];
        c8[tid * 8 + 5] = s;
    }
    __syncthreads();

    float ratio = get_ratio();
    int n0 = tile * 1024 + tid;
    float yf[4], xf[4], rr[4], gg[4], bb[4], fsq[4], dmin[4];
    int kb[4];
#pragma unroll
    for (int p = 0; p < 4; ++p) {
        int n = n0 + p * 256;
        int y = n / WW, x = n - y * WW;
        yf[p] = (float)y * ratio;
        xf[p] = (float)x * ratio;
        const float* pp = img + ((size_t)b * HWPIX + n) * 3;
        rr[p] = pp[0]; gg[p] = pp[1]; bb[p] = pp[2];
        float s = yf[p] * yf[p];             // no fma, seq adds (XLA reduce)
        s = s + xf[p] * xf[p];
        s = s + rr[p] * rr[p];
        s = s + gg[p] * gg[p];
        s = s + bb[p] * bb[p];
        fsq[p] = s;
        dmin[p] = INFINITY;
        kb[p] = 0;
    }

    for (int k = 0; k < KSEG; ++k) {
        float4 v0 = *reinterpret_cast<const float4*>(&c8[k * 8]);  // ds_read_b128
        float c4v = c8[k * 8 + 4];
        float csqv = c8[k * 8 + 5];
#pragma unroll
        for (int p = 0; p < 4; ++p) {
            // Eigen sgemm micro-kernel: sequential FMA chain over contracted dim
            float dot = yf[p] * v0.x;        // == fma(yf, c0, 0)
            dot = __fmaf_rn(xf[p], v0.y, dot);
            dot = __fmaf_rn(rr[p], v0.z, dot);
            dot = __fmaf_rn(gg[p], v0.w, dot);
            dot = __fmaf_rn(bb[p], c4v, dot);
            float d = (fsq[p] + csqv) - 2.0f * dot;   // three separately-rounded ops
            if (d < dmin[p]) { dmin[p] = d; kb[p] = k; }  // strict < == jnp.argmin
        }
    }

    if (mode == 1) {
#pragma unroll
        for (int p = 0; p < 4; ++p) {
            int n = n0 + p * 256;
            outLab[(size_t)b * HWPIX + n] = (float)kb[p];
            float* om = outMean + ((size_t)b * HWPIX + n) * 3;
            om[0] = c8[kb[p] * 8 + 2];
            om[1] = c8[kb[p] * 8 + 3];
            om[2] = c8[kb[p] * 8 + 4];
        }
        return;
    }

    // ---- tile-local stable counting sort (order: p, wave, lane == ascending n)
    int rank_w[4], cnt_w[4];
#pragma unroll
    for (int p = 0; p < 4; ++p) { rank_w[p] = 0; cnt_w[p] = 0; }
    for (int l = 0; l < 64; ++l) {
#pragma unroll
        for (int p = 0; p < 4; ++p) {
            int ll = __shfl(kb[p], l);
            if (ll == kb[p]) { cnt_w[p]++; if (l < lane) rank_w[p]++; }
        }
    }
#pragma unroll
    for (int p = 0; p < 4; ++p)
        if (rank_w[p] == 0) whist[(p * 4 + w) * KSEG + kb[p]] = cnt_w[p];
    __syncthreads();
    if (tid < KSEG) {
        int s = 0;
        for (int g = 0; g < 16; ++g) s += whist[g * KSEG + tid];
        tilecnt[tid] = s;
    }
    __syncthreads();
    if (tid < KSEG) {
        int bsum = 0;
        for (int j = 0; j < tid; ++j) bsum += tilecnt[j];
        loffs[tid] = bsum;
        cntT[((size_t)b * KSEG + tid) * NTILE + tile] = tilecnt[tid];
        startT[((size_t)b * KSEG + tid) * NTILE + tile] = bsum;
    }
    __syncthreads();

    float* tb = tileBuf + (size_t)(b * NTILE + tile) * 5 * 1024;
#pragma unroll
    for (int p = 0; p < 4; ++p) {
        int g = p * 4 + w;
        int r = rank_w[p];
        for (int g2 = 0; g2 < g; ++g2) r += whist[g2 * KSEG + kb[p]];
        int pos = loffs[kb[p]] + r;
        tb[0 * 1024 + pos] = yf[p];
        tb[1 * 1024 + pos] = xf[p];
        tb[2 * 1024 + pos] = rr[p];
        tb[3 * 1024 + pos] = gg[p];
        tb[4 * 1024 + pos] = bb[p];
    }
}

// One block per (batch,cluster). Shfl-scan the 49 descriptors -> dstL (+total
// sentinel). Output-indexed gather: thread j binary-searches dstL, copies 5
// channels coalesced into ubuf[.][j-c0]. Then 5 lanes run the EXACT ascending
// serial chains over ubuf (j ascending == pixel ascending).
__global__ void k_update(const float* __restrict__ tileBuf, const int* __restrict__ cntT,
                         const int* __restrict__ startT, float* __restrict__ centers) {
#pragma clang fp contract(off)
    __shared__ int srcL[NTILE];
    __shared__ int dstL[NTILE + 1];
    __shared__ float ubuf[5][UCH + 1];       // +1: channel rows staggered banks
    int k = blockIdx.x, b = blockIdx.y, tid = threadIdx.x;
    int lane = tid & 63;

    if (tid < 64) {
        int c = (lane < NTILE) ? cntT[((size_t)b * KSEG + k) * NTILE + lane] : 0;
        int s = (lane < NTILE) ? startT[((size_t)b * KSEG + k) * NTILE + lane] : 0;
        int incl = c;
        for (int d = 1; d < 64; d <<= 1) {   // Hillis-Steele inclusive scan
            int t = __shfl_up(incl, d);
            if (lane >= d) incl += t;
        }
        if (lane < NTILE) { srcL[lane] = s; dstL[lane] = incl - c; }
        if (lane == 63) dstL[NTILE] = incl;  // lanes >= NTILE have c=0 -> incl==total
    }
    __syncthreads();
    int total = dstL[NTILE];

    float acc = 0.f;
    for (int c0 = 0; c0 < total; c0 += UCH) {
        int m = min(UCH, total - c0);
        for (int jj = tid; jj < m; jj += 256) {
            int j = c0 + jj;
            int lo = 0, hi = NTILE;          // dstL[0]=0 <= j < dstL[NTILE]
            while (hi - lo > 1) {            // 6 steps
                int mid = (lo + hi) >> 1;
                if (dstL[mid] <= j) lo = mid; else hi = mid;
            }
            int src = srcL[lo] + (j - dstL[lo]);
            const float* tb = tileBuf + (size_t)(b * NTILE + lo) * 5 * 1024;
#pragma unroll
            for (int ch = 0; ch < 5; ++ch)
                ubuf[ch][jj] = tb[ch * 1024 + src];   // coalesced per channel
        }
        __syncthreads();
        if (tid < 5) {
            float a = acc;
            const float* bp = ubuf[tid];
            for (int i = 0; i < m; ++i) a = a + bp[i];   // exact ascending chain
            acc = a;
        }
        __syncthreads();
    }
    if (tid < 5 && total > 0) {              // where(counts>0, sums/counts, old)
        centers[(b * KSEG + k) * 5 + tid] = acc / (float)total;
    }
}

extern "C" void kernel_launch(void* const* d_in, const int* in_sizes, int n_in,
                              void* d_out, int out_size, void* d_ws, size_t ws_size,
                              hipStream_t stream) {
    const float* img = (const float*)d_in[0];
    float* outLab = (float*)d_out;                         // [8,224,224] labels as f32
    float* outMean = outLab + (size_t)BATCH * HWPIX;       // [8,224,224,3]

    char* ws = (char*)d_ws;
    float* centers = (float*)ws;  ws += (size_t)BATCH * KSEG * 5 * sizeof(float);
    float* tileBuf = (float*)ws;  ws += (size_t)BATCH * NTILE * 5 * 1024 * sizeof(float);
    int* cntT      = (int*)ws;    ws += (size_t)BATCH * KSEG * NTILE * sizeof(int);
    int* startT    = (int*)ws;    ws += (size_t)BATCH * KSEG * NTILE * sizeof(int);

    k_init<<<dim3(BATCH), 128, 0, stream>>>(img, centers);
    for (int it = 0; it < NITER; ++it) {
        k_assign<<<dim3(NTILE, BATCH), 256, 0, stream>>>(img, centers, tileBuf, cntT,
                                                         startT, outLab, outMean, 0);
        k_update<<<dim3(KSEG, BATCH), 256, 0, stream>>>(tileBuf, cntT, startT, centers);
    }
    k_assign<<<dim3(NTILE, BATCH), 256, 0, stream>>>(img, centers, tileBuf, cntT,
                                                     startT, outLab, outMean, 1);
}

// Round 12
// 383.154 us; speedup vs baseline: 1.9496x; 1.3446x over previous
//
#include <hip/hip_runtime.h>
#include <math.h>

// SLIC superpixel segmentation — bit-faithful f32 reimplementation of the JAX ref
// (XLA CPU semantics). Numerics decisions, all aimed at exact label match:
//  - dot(feats, centers) replicates Eigen sgemm: sequential k=0..4 FMA chain.
//  - f_sq / c_sq: rounded squares, sequential adds, NO fma (fp contract off).
//  - d = (f_sq + c_sq) - 2*dot, three separately-rounded ops.
//  - strict-< argmin (first occurrence, == jnp.argmin).
//  - segment_sum: EXACT ascending-pixel-index sequential adds per cluster.
// Structure: assign fuses a tile-local counting sort (1024-px tiles -> per-label
// segments in tileBuf + cnt/start); update concatenates the 49 tile segments in
// ascending tile order == ascending pixel order (bit-identical).
// R12 (vs R11's 515us):
//  - update drain: the 5-lane serial loop was scalar ds_read_b32 with ~120cyc
//    dependent latency per element (~25us/dispatch). Now float4 LDS reads
//    (rows padded to UCH+4 = 16B-aligned stride, banks staggered, conflict-
//    free) + unroll -> loads pipeline ahead, adds stay strictly ascending
//    (x,y,z,w) -> ~4cyc/elem, bit-identical.
//  - assign rank: 64-iter __shfl loop (256 ds_bpermute/wave) replaced by a
//    leader-ballot loop over DISTINCT labels in the wave (~3-6 iters). Same
//    rank/cnt integers.

#pragma clang fp contract(off)

#define BATCH 8
#define HH 224
#define WW 224
#define HWPIX (HH * WW)        // 50176
#define KSEG 100
#define NTILE 49               // 1024-px tiles per batch
#define NITER 10
#define UCH 1024               // update output chunk
#define UPITCH (UCH + 4)       // row stride: 4112B = 257*16, 16B-aligned, +4-bank stagger

__device__ __forceinline__ float get_ratio() {
    double S = sqrt((double)(HH * WW) / (double)KSEG);
    return (float)(10.0 / S);
}

__global__ void k_init(const float* __restrict__ img, float* __restrict__ centers) {
#pragma clang fp contract(off)
    int b = blockIdx.x;
    int k = threadIdx.x;
    if (k >= KSEG) return;
    int i = k / 10, j = k % 10;
    int y = (int)floor(((i + 0.5) * (double)HH) / 10.0);
    int x = (int)floor(((j + 0.5) * (double)WW) / 10.0);
    float ratio = get_ratio();
    int n = y * WW + x;
    const float* p = img + ((size_t)b * HWPIX + n) * 3;
    float* c = centers + (b * KSEG + k) * 5;
    c[0] = (float)y * ratio;
    c[1] = (float)x * ratio;
    c[2] = p[0];
    c[3] = p[1];
    c[4] = p[2];
}

// 4 pixels/thread: n = tile*1024 + p*256 + tid. Ascending n == lex (p, w, lane).
// mode 0: argmin + tile-local counting sort -> tileBuf segments + cnt/start.
// mode 1: final outputs only.
__global__ void k_assign(const float* __restrict__ img, const float* __restrict__ centers,
                         float* __restrict__ tileBuf, int* __restrict__ cntT,
                         int* __restrict__ startT, float* __restrict__ outLab,
                         float* __restrict__ outMean, int mode) {
#pragma clang fp contract(off)
    __shared__ float c8[KSEG * 8];   // [c0..c4, csq, pad, pad]
    __shared__ int whist[16 * KSEG]; // group g = p*4 + w, lex order == pixel order
    __shared__ int tilecnt[KSEG];
    __shared__ int loffs[KSEG];
    int b = blockIdx.y, tile = blockIdx.x, tid = threadIdx.x;
    int lane = tid & 63, w = tid >> 6;

    for (int i = tid; i < KSEG * 5; i += 256) {
        int k = i / 5, f = i - 5 * k;
        c8[k * 8 + f] = centers[(size_t)b * KSEG * 5 + i];
    }
    if (mode == 0)
        for (int i = tid; i < 16 * KSEG; i += 256) whist[i] = 0;
    __syncthreads();
    if (tid < KSEG) {
        const float* ck = c8 + tid * 8;
        float s = ck[0] * ck[0];             // XLA fused mul+reduce: no fma, seq adds
        s = s + ck[1] * ck[1];
        s = s + ck[2] * ck[2];
        s = s + ck[3] * ck[3];
        s = s + ck[4] * ck[4];
        c8[tid * 8 + 5] = s;
    }
    __syncthreads();

    float ratio = get_ratio();
    int n0 = tile * 1024 + tid;
    float yf[4], xf[4], rr[4], gg[4], bb[4], fsq[4], dmin[4];
    int kb[4];
#pragma unroll
    for (int p = 0; p < 4; ++p) {
        int n = n0 + p * 256;
        int y = n / WW, x = n - y * WW;
        yf[p] = (float)y * ratio;
        xf[p] = (float)x * ratio;
        const float* pp = img + ((size_t)b * HWPIX + n) * 3;
        rr[p] = pp[0]; gg[p] = pp[1]; bb[p] = pp[2];
        float s = yf[p] * yf[p];             // no fma, seq adds (XLA reduce)
        s = s + xf[p] * xf[p];
        s = s + rr[p] * rr[p];
        s = s + gg[p] * gg[p];
        s = s + bb[p] * bb[p];
        fsq[p] = s;
        dmin[p] = INFINITY;
        kb[p] = 0;
    }

    for (int k = 0; k < KSEG; ++k) {
        float4 v0 = *reinterpret_cast<const float4*>(&c8[k * 8]);  // ds_read_b128
        float c4v = c8[k * 8 + 4];
        float csqv = c8[k * 8 + 5];
#pragma unroll
        for (int p = 0; p < 4; ++p) {
            // Eigen sgemm micro-kernel: sequential FMA chain over contracted dim
            float dot = yf[p] * v0.x;        // == fma(yf, c0, 0)
            dot = __fmaf_rn(xf[p], v0.y, dot);
            dot = __fmaf_rn(rr[p], v0.z, dot);
            dot = __fmaf_rn(gg[p], v0.w, dot);
            dot = __fmaf_rn(bb[p], c4v, dot);
            float d = (fsq[p] + csqv) - 2.0f * dot;   // three separately-rounded ops
            if (d < dmin[p]) { dmin[p] = d; kb[p] = k; }  // strict < == jnp.argmin
        }
    }

    if (mode == 1) {
#pragma unroll
        for (int p = 0; p < 4; ++p) {
            int n = n0 + p * 256;
            outLab[(size_t)b * HWPIX + n] = (float)kb[p];
            float* om = outMean + ((size_t)b * HWPIX + n) * 3;
            om[0] = c8[kb[p] * 8 + 2];
            om[1] = c8[kb[p] * 8 + 3];
            om[2] = c8[kb[p] * 8 + 4];
        }
        return;
    }

    // ---- tile-local stable counting sort (order: p, wave, lane == ascending n)
    // Leader-ballot rank: iterate over DISTINCT labels present in the wave.
    unsigned long long lmask_lt = (lane == 0) ? 0ull : (~0ull >> (64 - lane));
    int rank_w[4], cnt_w[4];
#pragma unroll
    for (int p = 0; p < 4; ++p) {
        unsigned long long todo = __ballot(1);       // all active lanes
        while (todo) {
            int leader = __builtin_ctzll(todo);
            int lval = __shfl(kb[p], leader);
            unsigned long long mset = __ballot(kb[p] == lval);
            if (kb[p] == lval) {
                cnt_w[p] = (int)__popcll(mset);
                rank_w[p] = (int)__popcll(mset & lmask_lt);
            }
            todo &= ~mset;
        }
    }
#pragma unroll
    for (int p = 0; p < 4; ++p)
        if (rank_w[p] == 0) whist[(p * 4 + w) * KSEG + kb[p]] = cnt_w[p];
    __syncthreads();
    if (tid < KSEG) {
        int s = 0;
        for (int g = 0; g < 16; ++g) s += whist[g * KSEG + tid];
        tilecnt[tid] = s;
    }
    __syncthreads();
    if (tid < KSEG) {
        int bsum = 0;
        for (int j = 0; j < tid; ++j) bsum += tilecnt[j];
        loffs[tid] = bsum;
        cntT[((size_t)b * KSEG + tid) * NTILE + tile] = tilecnt[tid];
        startT[((size_t)b * KSEG + tid) * NTILE + tile] = bsum;
    }
    __syncthreads();

    float* tb = tileBuf + (size_t)(b * NTILE + tile) * 5 * 1024;
#pragma unroll
    for (int p = 0; p < 4; ++p) {
        int g = p * 4 + w;
        int r = rank_w[p];
        for (int g2 = 0; g2 < g; ++g2) r += whist[g2 * KSEG + kb[p]];
        int pos = loffs[kb[p]] + r;
        tb[0 * 1024 + pos] = yf[p];
        tb[1 * 1024 + pos] = xf[p];
        tb[2 * 1024 + pos] = rr[p];
        tb[3 * 1024 + pos] = gg[p];
        tb[4 * 1024 + pos] = bb[p];
    }
}

// One block per (batch,cluster). Shfl-scan the 49 descriptors -> dstL (+total
// sentinel). Output-indexed gather: thread j binary-searches dstL, copies 5
// channels coalesced into ubuf[.][j-c0]. Then 5 lanes run the EXACT ascending
// serial chains via pipelined float4 LDS reads (adds in x,y,z,w index order).
__global__ void k_update(const float* __restrict__ tileBuf, const int* __restrict__ cntT,
                         const int* __restrict__ startT, float* __restrict__ centers) {
#pragma clang fp contract(off)
    __shared__ int srcL[NTILE];
    __shared__ int dstL[NTILE + 1];
    __shared__ float ubuf[5][UPITCH];        // row stride 4112B: 16B-aligned, staggered
    int k = blockIdx.x, b = blockIdx.y, tid = threadIdx.x;
    int lane = tid & 63;

    if (tid < 64) {
        int c = (lane < NTILE) ? cntT[((size_t)b * KSEG + k) * NTILE + lane] : 0;
        int s = (lane < NTILE) ? startT[((size_t)b * KSEG + k) * NTILE + lane] : 0;
        int incl = c;
        for (int d = 1; d < 64; d <<= 1) {   // Hillis-Steele inclusive scan
            int t = __shfl_up(incl, d);
            if (lane >= d) incl += t;
        }
        if (lane < NTILE) { srcL[lane] = s; dstL[lane] = incl - c; }
        if (lane == 63) dstL[NTILE] = incl;  // lanes >= NTILE have c=0 -> incl==total
    }
    __syncthreads();
    int total = dstL[NTILE];

    float acc = 0.f;
    for (int c0 = 0; c0 < total; c0 += UCH) {
        int m = min(UCH, total - c0);
        for (int jj = tid; jj < m; jj += 256) {
            int j = c0 + jj;
            int lo = 0, hi = NTILE;          // dstL[0]=0 <= j < dstL[NTILE]
            while (hi - lo > 1) {            // 6 steps
                int mid = (lo + hi) >> 1;
                if (dstL[mid] <= j) lo = mid; else hi = mid;
            }
            int src = srcL[lo] + (j - dstL[lo]);
            const float* tb = tileBuf + (size_t)(b * NTILE + lo) * 5 * 1024;
#pragma unroll
            for (int ch = 0; ch < 5; ++ch)
                ubuf[ch][jj] = tb[ch * 1024 + src];   // coalesced per channel
        }
        __syncthreads();
        if (tid < 5) {
            float a = acc;
            const float4* bp4 = reinterpret_cast<const float4*>(&ubuf[tid][0]);
            int nf4 = m >> 2;
#pragma unroll 4
            for (int i = 0; i < nf4; ++i) {  // loads pipeline; adds ascending
                float4 v = bp4[i];
                a = a + v.x;
                a = a + v.y;
                a = a + v.z;
                a = a + v.w;
            }
            for (int i = nf4 << 2; i < m; ++i) a = a + ubuf[tid][i];
            acc = a;
        }
        __syncthreads();
    }
    if (tid < 5 && total > 0) {              // where(counts>0, sums/counts, old)
        centers[(b * KSEG + k) * 5 + tid] = acc / (float)total;
    }
}

extern "C" void kernel_launch(void* const* d_in, const int* in_sizes, int n_in,
                              void* d_out, int out_size, void* d_ws, size_t ws_size,
                              hipStream_t stream) {
    const float* img = (const float*)d_in[0];
    float* outLab = (float*)d_out;                         // [8,224,224] labels as f32
    float* outMean = outLab + (size_t)BATCH * HWPIX;       // [8,224,224,3]

    char* ws = (char*)d_ws;
    float* centers = (float*)ws;  ws += (size_t)BATCH * KSEG * 5 * sizeof(float);
    float* tileBuf = (float*)ws;  ws += (size_t)BATCH * NTILE * 5 * 1024 * sizeof(float);
    int* cntT      = (int*)ws;    ws += (size_t)BATCH * KSEG * NTILE * sizeof(int);
    int* startT    = (int*)ws;    ws += (size_t)BATCH * KSEG * NTILE * sizeof(int);

    k_init<<<dim3(BATCH), 128, 0, stream>>>(img, centers);
    for (int it = 0; it < NITER; ++it) {
        k_assign<<<dim3(NTILE, BATCH), 256, 0, stream>>>(img, centers, tileBuf, cntT,
                                                         startT, outLab, outMean, 0);
        k_update<<<dim3(KSEG, BATCH), 256, 0, stream>>>(tileBuf, cntT, startT, centers);
    }
    k_assign<<<dim3(NTILE, BATCH), 256, 0, stream>>>(img, centers, tileBuf, cntT,
                                                     startT, outLab, outMean, 1);
}

// Round 13
// 370.462 us; speedup vs baseline: 2.0164x; 1.0343x over previous
//
#include <hip/hip_runtime.h>
#include <math.h>

// SLIC superpixel segmentation — bit-faithful f32 reimplementation of the JAX ref
// (XLA CPU semantics). Numerics decisions, all aimed at exact label match:
//  - dot(feats, centers) replicates Eigen sgemm: sequential k=0..4 FMA chain.
//  - f_sq / c_sq: rounded squares, sequential adds, NO fma (fp contract off).
//  - d = (f_sq + c_sq) - 2*dot, three separately-rounded ops.
//  - strict-< argmin (first occurrence, == jnp.argmin).
//  - segment_sum: EXACT ascending-pixel-index sequential adds per cluster.
// Structure: assign fuses a tile-local counting sort (per-label segments in
// tileBuf + cnt/start); update concatenates tile segments in ascending tile
// order == ascending pixel order (bit-identical).
// R13 (vs R12's 383us): assign grid was 392 blocks = 1.53/CU -> ~2x imbalance
// (20us vs 5.6us VALU roofline). Now 2 px/thread, 512-px tiles, NTILE=98,
// grid 784 = 3.06/CU (imbalance 1.3). whist groups 8 (lex (p,w) == ascending
// n), update scans 98 descriptors in two 64-chunks w/ carry, 7-step bsearch.
// Float math and global add order untouched -> outputs bit-identical.

#pragma clang fp contract(off)

#define BATCH 8
#define HH 224
#define WW 224
#define HWPIX (HH * WW)        // 50176
#define KSEG 100
#define TPX 512                // pixels per tile
#define NTILE 98               // 512-px tiles per batch (98*512 == 50176)
#define NITER 10
#define UCH 1024               // update output chunk
#define UPITCH (UCH + 4)       // row stride: 4112B = 257*16, 16B-aligned, staggered banks

__device__ __forceinline__ float get_ratio() {
    double S = sqrt((double)(HH * WW) / (double)KSEG);
    return (float)(10.0 / S);
}

__global__ void k_init(const float* __restrict__ img, float* __restrict__ centers) {
#pragma clang fp contract(off)
    int b = blockIdx.x;
    int k = threadIdx.x;
    if (k >= KSEG) return;
    int i = k / 10, j = k % 10;
    int y = (int)floor(((i + 0.5) * (double)HH) / 10.0);
    int x = (int)floor(((j + 0.5) * (double)WW) / 10.0);
    float ratio = get_ratio();
    int n = y * WW + x;
    const float* p = img + ((size_t)b * HWPIX + n) * 3;
    float* c = centers + (b * KSEG + k) * 5;
    c[0] = (float)y * ratio;
    c[1] = (float)x * ratio;
    c[2] = p[0];
    c[3] = p[1];
    c[4] = p[2];
}

// 2 pixels/thread: n = tile*512 + p*256 + tid. Ascending n == lex (p, w, lane).
// mode 0: argmin + tile-local counting sort -> tileBuf segments + cnt/start.
// mode 1: final outputs only.
__global__ void k_assign(const float* __restrict__ img, const float* __restrict__ centers,
                         float* __restrict__ tileBuf, int* __restrict__ cntT,
                         int* __restrict__ startT, float* __restrict__ outLab,
                         float* __restrict__ outMean, int mode) {
#pragma clang fp contract(off)
    __shared__ float c8[KSEG * 8];   // [c0..c4, csq, pad, pad]
    __shared__ int whist[8 * KSEG];  // group g = p*4 + w, lex order == pixel order
    __shared__ int tilecnt[KSEG];
    __shared__ int loffs[KSEG];
    int b = blockIdx.y, tile = blockIdx.x, tid = threadIdx.x;
    int lane = tid & 63, w = tid >> 6;

    for (int i = tid; i < KSEG * 5; i += 256) {
        int k = i / 5, f = i - 5 * k;
        c8[k * 8 + f] = centers[(size_t)b * KSEG * 5 + i];
    }
    if (mode == 0)
        for (int i = tid; i < 8 * KSEG; i += 256) whist[i] = 0;
    __syncthreads();
    if (tid < KSEG) {
        const float* ck = c8 + tid * 8;
        float s = ck[0] * ck[0];             // XLA fused mul+reduce: no fma, seq adds
        s = s + ck[1] * ck[1];
        s = s + ck[2] * ck[2];
        s = s + ck[3] * ck[3];
        s = s + ck[4] * ck[4];
        c8[tid * 8 + 5] = s;
    }
    __syncthreads();

    float ratio = get_ratio();
    int n0 = tile * TPX + tid;
    float yf[2], xf[2], rr[2], gg[2], bb[2], fsq[2], dmin[2];
    int kb[2];
#pragma unroll
    for (int p = 0; p < 2; ++p) {
        int n = n0 + p * 256;
        int y = n / WW, x = n - y * WW;
        yf[p] = (float)y * ratio;
        xf[p] = (float)x * ratio;
        const float* pp = img + ((size_t)b * HWPIX + n) * 3;
        rr[p] = pp[0]; gg[p] = pp[1]; bb[p] = pp[2];
        float s = yf[p] * yf[p];             // no fma, seq adds (XLA reduce)
        s = s + xf[p] * xf[p];
        s = s + rr[p] * rr[p];
        s = s + gg[p] * gg[p];
        s = s + bb[p] * bb[p];
        fsq[p] = s;
        dmin[p] = INFINITY;
        kb[p] = 0;
    }

    for (int k = 0; k < KSEG; ++k) {
        float4 v0 = *reinterpret_cast<const float4*>(&c8[k * 8]);  // ds_read_b128
        float c4v = c8[k * 8 + 4];
        float csqv = c8[k * 8 + 5];
#pragma unroll
        for (int p = 0; p < 2; ++p) {
            // Eigen sgemm micro-kernel: sequential FMA chain over contracted dim
            float dot = yf[p] * v0.x;        // == fma(yf, c0, 0)
            dot = __fmaf_rn(xf[p], v0.y, dot);
            dot = __fmaf_rn(rr[p], v0.z, dot);
            dot = __fmaf_rn(gg[p], v0.w, dot);
            dot = __fmaf_rn(bb[p], c4v, dot);
            float d = (fsq[p] + csqv) - 2.0f * dot;   // three separately-rounded ops
            if (d < dmin[p]) { dmin[p] = d; kb[p] = k; }  // strict < == jnp.argmin
        }
    }

    if (mode == 1) {
#pragma unroll
        for (int p = 0; p < 2; ++p) {
            int n = n0 + p * 256;
            outLab[(size_t)b * HWPIX + n] = (float)kb[p];
            float* om = outMean + ((size_t)b * HWPIX + n) * 3;
            om[0] = c8[kb[p] * 8 + 2];
            om[1] = c8[kb[p] * 8 + 3];
            om[2] = c8[kb[p] * 8 + 4];
        }
        return;
    }

    // ---- tile-local stable counting sort (order: p, wave, lane == ascending n)
    // Leader-ballot rank over DISTINCT labels present in the wave.
    unsigned long long lmask_lt = (lane == 0) ? 0ull : (~0ull >> (64 - lane));
    int rank_w[2], cnt_w[2];
#pragma unroll
    for (int p = 0; p < 2; ++p) {
        unsigned long long todo = __ballot(1);       // all active lanes
        while (todo) {
            int leader = __builtin_ctzll(todo);
            int lval = __shfl(kb[p], leader);
            unsigned long long mset = __ballot(kb[p] == lval);
            if (kb[p] == lval) {
                cnt_w[p] = (int)__popcll(mset);
                rank_w[p] = (int)__popcll(mset & lmask_lt);
            }
            todo &= ~mset;
        }
    }
#pragma unroll
    for (int p = 0; p < 2; ++p)
        if (rank_w[p] == 0) whist[(p * 4 + w) * KSEG + kb[p]] = cnt_w[p];
    __syncthreads();
    if (tid < KSEG) {
        int s = 0;
        for (int g = 0; g < 8; ++g) s += whist[g * KSEG + tid];
        tilecnt[tid] = s;
    }
    __syncthreads();
    if (tid < KSEG) {
        int bsum = 0;
        for (int j = 0; j < tid; ++j) bsum += tilecnt[j];
        loffs[tid] = bsum;
        cntT[((size_t)b * KSEG + tid) * NTILE + tile] = tilecnt[tid];
        startT[((size_t)b * KSEG + tid) * NTILE + tile] = bsum;
    }
    __syncthreads();

    float* tb = tileBuf + (size_t)(b * NTILE + tile) * 5 * TPX;
#pragma unroll
    for (int p = 0; p < 2; ++p) {
        int g = p * 4 + w;
        int r = rank_w[p];
        for (int g2 = 0; g2 < g; ++g2) r += whist[g2 * KSEG + kb[p]];
        int pos = loffs[kb[p]] + r;
        tb[0 * TPX + pos] = yf[p];
        tb[1 * TPX + pos] = xf[p];
        tb[2 * TPX + pos] = rr[p];
        tb[3 * TPX + pos] = gg[p];
        tb[4 * TPX + pos] = bb[p];
    }
}

// One block per (batch,cluster). Chunked shfl-scan of the 98 descriptors ->
// dstL (+total sentinel). Output-indexed gather: thread j binary-searches dstL
// (7 steps), copies 5 channels coalesced into ubuf. Then 5 lanes run the EXACT
// ascending serial chains via pipelined float4 LDS reads (x,y,z,w index order).
__global__ void k_update(const float* __restrict__ tileBuf, const int* __restrict__ cntT,
                         const int* __restrict__ startT, float* __restrict__ centers) {
#pragma clang fp contract(off)
    __shared__ int srcL[NTILE];
    __shared__ int dstL[NTILE + 1];
    __shared__ float ubuf[5][UPITCH];
    int k = blockIdx.x, b = blockIdx.y, tid = threadIdx.x;
    int lane = tid & 63;

    if (tid < 64) {
        int carry = 0;
        for (int c0 = 0; c0 < NTILE; c0 += 64) {
            int idx = c0 + lane;
            int c = (idx < NTILE) ? cntT[((size_t)b * KSEG + k) * NTILE + idx] : 0;
            int s = (idx < NTILE) ? startT[((size_t)b * KSEG + k) * NTILE + idx] : 0;
            int incl = c;
            for (int d = 1; d < 64; d <<= 1) {   // Hillis-Steele inclusive scan
                int t = __shfl_up(incl, d);
                if (lane >= d) incl += t;
            }
            if (idx < NTILE) { srcL[idx] = s; dstL[idx] = carry + incl - c; }
            carry += __shfl(incl, 63);
        }
        if (lane == 0) dstL[NTILE] = carry;
    }
    __syncthreads();
    int total = dstL[NTILE];

    float acc = 0.f;
    for (int c0 = 0; c0 < total; c0 += UCH) {
        int m = min(UCH, total - c0);
        for (int jj = tid; jj < m; jj += 256) {
            int j = c0 + jj;
            int lo = 0, hi = NTILE;          // dstL[0]=0 <= j < dstL[NTILE]
            while (hi - lo > 1) {            // 7 steps
                int mid = (lo + hi) >> 1;
                if (dstL[mid] <= j) lo = mid; else hi = mid;
            }
            int src = srcL[lo] + (j - dstL[lo]);
            const float* tb = tileBuf + (size_t)(b * NTILE + lo) * 5 * TPX;
#pragma unroll
            for (int ch = 0; ch < 5; ++ch)
                ubuf[ch][jj] = tb[ch * TPX + src];    // coalesced per channel
        }
        __syncthreads();
        if (tid < 5) {
            float a = acc;
            const float4* bp4 = reinterpret_cast<const float4*>(&ubuf[tid][0]);
            int nf4 = m >> 2;
#pragma unroll 4
            for (int i = 0; i < nf4; ++i) {  // loads pipeline; adds ascending
                float4 v = bp4[i];
                a = a + v.x;
                a = a + v.y;
                a = a + v.z;
                a = a + v.w;
            }
            for (int i = nf4 << 2; i < m; ++i) a = a + ubuf[tid][i];
            acc = a;
        }
        __syncthreads();
    }
    if (tid < 5 && total > 0) {              // where(counts>0, sums/counts, old)
        centers[(b * KSEG + k) * 5 + tid] = acc / (float)total;
    }
}

extern "C" void kernel_launch(void* const* d_in, const int* in_sizes, int n_in,
                              void* d_out, int out_size, void* d_ws, size_t ws_size,
                              hipStream_t stream) {
    const float* img = (const float*)d_in[0];
    float* outLab = (float*)d_out;                         // [8,224,224] labels as f32
    float* outMean = outLab + (size_t)BATCH * HWPIX;       // [8,224,224,3]

    char* ws = (char*)d_ws;
    float* centers = (float*)ws;  ws += (size_t)BATCH * KSEG * 5 * sizeof(float);
    float* tileBuf = (float*)ws;  ws += (size_t)BATCH * NTILE * 5 * TPX * sizeof(float);
    int* cntT      = (int*)ws;    ws += (size_t)BATCH * KSEG * NTILE * sizeof(int);
    int* startT    = (int*)ws;    ws += (size_t)BATCH * KSEG * NTILE * sizeof(int);

    k_init<<<dim3(BATCH), 128, 0, stream>>>(img, centers);
    for (int it = 0; it < NITER; ++it) {
        k_assign<<<dim3(NTILE, BATCH), 256, 0, stream>>>(img, centers, tileBuf, cntT,
                                                         startT, outLab, outMean, 0);
        k_update<<<dim3(KSEG, BATCH), 256, 0, stream>>>(tileBuf, cntT, startT, centers);
    }
    k_assign<<<dim3(NTILE, BATCH), 256, 0, stream>>>(img, centers, tileBuf, cntT,
                                                     startT, outLab, outMean, 1);
}